// Round 1
// baseline (3109.426 us; speedup 1.0000x reference)
//
#include <hip/hip_runtime.h>
#include <cstdint>
#include <cstddef>

typedef __bf16 bf16x8 __attribute__((ext_vector_type(8)));
typedef float  f32x4  __attribute__((ext_vector_type(4)));

typedef __attribute__((address_space(1))) void v_as1;
typedef __attribute__((address_space(3))) void v_as3;

#define NTOK 100352      // 2*224*224
#define DIMC 768
#define NHEAD 12
#define IMG 224
#define WN 7
#define WL 49

__device__ __forceinline__ unsigned short f2bf(float f) {
    uint32_t u = __float_as_uint(f);
    uint32_t r = (u + 0x7FFFu + ((u >> 16) & 1u)) >> 16;
    return (unsigned short)r;
}
__device__ __forceinline__ float bf2f(unsigned short u) {
    return __uint_as_float(((uint32_t)u) << 16);
}

__device__ __forceinline__ void async_cp16(const void* g, void* l) {
    __builtin_amdgcn_global_load_lds((v_as1*)g, (v_as3*)l, 16, 0, 0);
}

// ---------------- hi/lo bf16 split ----------------
__global__ __launch_bounds__(256) void hilo_kernel(const float* __restrict__ in,
        unsigned short* __restrict__ hi, unsigned short* __restrict__ lo,
        int n4, int has_lo) {
    int idx = blockIdx.x * 256 + threadIdx.x;
    int stride = gridDim.x * 256;
    for (int i = idx; i < n4; i += stride) {
        float4 v = reinterpret_cast<const float4*>(in)[i];
        ushort4 h;
        h.x = f2bf(v.x); h.y = f2bf(v.y); h.z = f2bf(v.z); h.w = f2bf(v.w);
        reinterpret_cast<ushort4*>(hi)[i] = h;
        if (has_lo) {
            ushort4 l;
            l.x = f2bf(v.x - bf2f(h.x));
            l.y = f2bf(v.y - bf2f(h.y));
            l.z = f2bf(v.z - bf2f(h.z));
            l.w = f2bf(v.w - bf2f(h.w));
            reinterpret_cast<ushort4*>(lo)[i] = l;
        }
    }
}

// ---------------- 128x128x32 bf16 MFMA GEMM, C = A * B^T ----------------
// A: M x K row-major bf16, B: N x K row-major bf16 (i.e. B^T layout).
// nseg=3: C = Ahi*Bhi + Alo*Bhi + Ahi*Blo (split-fp32 emulation). nseg=1: Ahi*Bhi.
// Output: Cf (fp32) if non-null, else Cb (bf16). M%128==0, N%128==0, K%32==0.
#define BM 128
#define BN 128
#define BK 32
__global__ __launch_bounds__(256) void gemm_bt(
    const unsigned short* __restrict__ Ahi, const unsigned short* __restrict__ Alo,
    const unsigned short* __restrict__ Bhi, const unsigned short* __restrict__ Blo,
    float* __restrict__ Cf, unsigned short* __restrict__ Cb,
    int M, int N, int K, int nseg)
{
    __shared__ unsigned short lA[BM * BK];   // row-major 128x32, no pad (global_load_lds order)
    __shared__ unsigned short lB[BN * BK];

    const int tid  = threadIdx.x;
    const int wave = tid >> 6;
    const int lane = tid & 63;

    const int nTiles = N / BN;
    const int bm = blockIdx.x / nTiles;
    const int bn = blockIdx.x % nTiles;
    const int m0 = bm * BM, n0 = bn * BN;

    const int wm = (wave & 1) * 64;
    const int wn = (wave >> 1) * 64;

    f32x4 acc[4][4];
#pragma unroll
    for (int i = 0; i < 4; i++)
#pragma unroll
        for (int j = 0; j < 4; j++) acc[i][j] = (f32x4){0.f, 0.f, 0.f, 0.f};

    // staging: 512 chunks of 16B per tile; thread handles chunks tid and tid+256
    const int c0 = tid, c1 = tid + 256;
    const int ar0 = c0 >> 2, ac0 = (c0 & 3) * 8;
    const int ar1 = c1 >> 2, ac1 = (c1 & 3) * 8;
    unsigned short* lA0 = &lA[(size_t)(wave * 64) * 8];
    unsigned short* lA1 = &lA[(size_t)(256 + wave * 64) * 8];
    unsigned short* lB0 = &lB[(size_t)(wave * 64) * 8];
    unsigned short* lB1 = &lB[(size_t)(256 + wave * 64) * 8];

    const int lquad = lane >> 4;
    const int l16   = lane & 15;

    for (int seg = 0; seg < nseg; ++seg) {
        const unsigned short* As = (seg == 1) ? Alo : Ahi;
        const unsigned short* Bs = (seg == 2) ? Blo : Bhi;
        const unsigned short* Ab = As + (size_t)m0 * K;
        const unsigned short* Bb = Bs + (size_t)n0 * K;
        for (int kk = 0; kk < K; kk += BK) {
            async_cp16(Ab + (size_t)ar0 * K + kk + ac0, lA0);
            async_cp16(Ab + (size_t)ar1 * K + kk + ac1, lA1);
            async_cp16(Bb + (size_t)ar0 * K + kk + ac0, lB0);
            async_cp16(Bb + (size_t)ar1 * K + kk + ac1, lB1);
            __syncthreads();
            bf16x8 a[4], b[4];
#pragma unroll
            for (int i = 0; i < 4; i++)
                a[i] = *reinterpret_cast<const bf16x8*>(&lA[(size_t)(wm + i * 16 + l16) * BK + lquad * 8]);
#pragma unroll
            for (int j = 0; j < 4; j++)
                b[j] = *reinterpret_cast<const bf16x8*>(&lB[(size_t)(wn + j * 16 + l16) * BK + lquad * 8]);
#pragma unroll
            for (int i = 0; i < 4; i++)
#pragma unroll
                for (int j = 0; j < 4; j++)
                    acc[i][j] = __builtin_amdgcn_mfma_f32_16x16x32_bf16(a[i], b[j], acc[i][j], 0, 0, 0);
            __syncthreads();
        }
    }

    // epilogue: C/D layout col = lane&15, row = (lane>>4)*4 + r
    if (Cf) {
#pragma unroll
        for (int i = 0; i < 4; i++) {
            int rb = m0 + wm + i * 16 + lquad * 4;
#pragma unroll
            for (int r = 0; r < 4; r++) {
                float* crow = Cf + (size_t)(rb + r) * N + n0 + wn + l16;
#pragma unroll
                for (int j = 0; j < 4; j++) crow[j * 16] = acc[i][j][r];
            }
        }
    } else {
#pragma unroll
        for (int i = 0; i < 4; i++) {
            int rb = m0 + wm + i * 16 + lquad * 4;
#pragma unroll
            for (int r = 0; r < 4; r++) {
                unsigned short* crow = Cb + (size_t)(rb + r) * N + n0 + wn + l16;
#pragma unroll
                for (int j = 0; j < 4; j++) crow[j * 16] = f2bf(acc[i][j][r]);
            }
        }
    }
}

// ---------------- windowed attention, one block per (window, head) ----------------
// qk: NTOK x 1536 fp32 (q cols 0..767, k cols 768..1535); vbuf: NTOK x 768 bf16
// attnout: NTOK x 768 bf16. Rows are in x-order; window gather == output scatter.
__global__ __launch_bounds__(256) void attn_kernel(
    const float* __restrict__ qk,
    const unsigned short* __restrict__ vbuf,
    unsigned short* __restrict__ attnout)
{
    const int h   = blockIdx.x % NHEAD;
    const int win = blockIdx.x / NHEAD;
    const int b   = win >> 10;          // /1024
    const int wy  = (win >> 5) & 31;
    const int wx  = win & 31;

    __shared__ float sq[WL][65];
    __shared__ float sk[WL][65];
    __shared__ float sv[WL][65];
    __shared__ float sS[WL][WL];
    __shared__ float invq[WL], invk[WL], rsum[WL];
    __shared__ int   rowidx[WL];

    const int tid = threadIdx.x;

    if (tid < WL) {
        int i = tid / WN, j = tid % WN;
        int ys = (wy * WN + i + 3) % IMG;
        int xs = (wx * WN + j + 3) % IMG;
        rowidx[tid] = b * (IMG * IMG) + ys * IMG + xs;
    }
    __syncthreads();

    // stage q,k with 2D RoPE (pairs d, d+32); angle = (d<16 ? i : j) * 100^(-(d&15)/16)
    const float LOG2_100_D16 = 0.41524101186092f;  // log2(100)/16
    for (int e = tid; e < WL * 32; e += 256) {
        int l = e >> 5, d = e & 31;
        int i = l / WN, j = l % WN;
        float pos = (d < 16) ? (float)i : (float)j;
        float ang = pos * exp2f(-(float)(d & 15) * LOG2_100_D16);
        float s, c;
        __sincosf(ang, &s, &c);
        size_t base = (size_t)rowidx[l] * 1536 + h * 64;
        float q1 = qk[base + d], q2 = qk[base + d + 32];
        sq[l][d]      = q1 * c - q2 * s;
        sq[l][d + 32] = q1 * s + q2 * c;
        float k1 = qk[base + 768 + d], k2 = qk[base + 768 + d + 32];
        sk[l][d]      = k1 * c - k2 * s;
        sk[l][d + 32] = k1 * s + k2 * c;
    }
    for (int e = tid; e < WL * 64; e += 256) {
        int l = e >> 6, d = e & 63;
        sv[l][d] = bf2f(vbuf[(size_t)rowidx[l] * 768 + h * 64 + d]);
    }
    __syncthreads();

    // inverse norms (clip at 1e-12 like reference)
    if (tid < 2 * WL) {
        int l = (tid < WL) ? tid : tid - WL;
        const float* p = (tid < WL) ? sq[l] : sk[l];
        float s = 0.f;
#pragma unroll
        for (int d = 0; d < 64; d++) s += p[d] * p[d];
        float inv = 1.f / fmaxf(sqrtf(s), 1e-12f);
        if (tid < WL) invq[l] = inv; else invk[l] = inv;
    }
    __syncthreads();

    // scores S = 100 * (q_hat . k_hat)
    for (int e = tid; e < WL * WL; e += 256) {
        int a = e / WL, bb = e % WL;
        float s = 0.f;
#pragma unroll
        for (int d = 0; d < 64; d++) s += sq[a][d] * sk[bb][d];
        sS[a][bb] = s * invq[a] * invk[bb] * 100.f;
    }
    __syncthreads();

    // softmax rows: 4 threads per row (4-lane shuffle groups, wave-aligned)
    if (tid < WL * 4) {
        int a = tid >> 2, s4 = tid & 3;
        float m = -1e30f;
        for (int bb = s4; bb < WL; bb += 4) m = fmaxf(m, sS[a][bb]);
        m = fmaxf(m, __shfl_xor(m, 1));
        m = fmaxf(m, __shfl_xor(m, 2));
        float sum = 0.f;
        for (int bb = s4; bb < WL; bb += 4) {
            float p = __expf(sS[a][bb] - m);
            sS[a][bb] = p;
            sum += p;
        }
        sum += __shfl_xor(sum, 1);
        sum += __shfl_xor(sum, 2);
        if (s4 == 0) rsum[a] = 1.f / sum;
    }
    __syncthreads();

    // O = P V (normalize by rsum), scatter back in x-order
    for (int e = tid; e < WL * 64; e += 256) {
        int a = e >> 6, d = e & 63;
        float o = 0.f;
        for (int bb = 0; bb < WL; bb++) o += sS[a][bb] * sv[bb][d];
        attnout[(size_t)rowidx[a] * 768 + h * 64 + d] = f2bf(o * rsum[a]);
    }
}

extern "C" void kernel_launch(void* const* d_in, const int* in_sizes, int n_in,
                              void* d_out, int out_size, void* d_ws, size_t ws_size,
                              hipStream_t stream) {
    const float* x      = (const float*)d_in[0];
    const float* qkv_w  = (const float*)d_in[1];
    const float* proj_w = (const float*)d_in[2];
    float* out = (float*)d_out;

    char* ws = (char*)d_ws;
    const size_t XE    = (size_t)NTOK * DIMC;       // 77,070,336
    const size_t WQKV  = (size_t)3 * DIMC * DIMC;   // 1,769,472
    const size_t WPROJ = (size_t)DIMC * DIMC;       // 589,824

    unsigned short* x_hi = (unsigned short*)ws;     // XE elts
    unsigned short* x_lo = x_hi + XE;               // XE elts
    unsigned short* w_hi = x_lo + XE;               // WQKV
    unsigned short* w_lo = w_hi + WQKV;             // WQKV
    unsigned short* p_hi = w_lo + WQKV;             // WPROJ
    float* qkbuf = (float*)(p_hi + WPROJ);          // NTOK*1536 fp32
    unsigned short* vbuf    = x_lo;                 // overlay: x_lo dead after qk GEMM
    unsigned short* attnout = x_hi;                 // overlay: x_hi dead after v GEMM

    size_t need = (size_t)((char*)(qkbuf + (size_t)NTOK * 1536) - ws); // 933,101,568
    if (ws_size < need) return;

    hilo_kernel<<<8192, 256, 0, stream>>>(x, x_hi, x_lo, (int)(XE / 4), 1);
    hilo_kernel<<<1728, 256, 0, stream>>>(qkv_w, w_hi, w_lo, (int)(WQKV / 4), 1);
    hilo_kernel<<<576, 256, 0, stream>>>(proj_w, p_hi, (unsigned short*)nullptr, (int)(WPROJ / 4), 0);

    // q,k: 3-segment split-bf16, fp32 out (precision-critical: logits = 100*dot)
    gemm_bt<<<(NTOK / 128) * (1536 / 128), 256, 0, stream>>>(
        x_hi, x_lo, w_hi, w_lo, qkbuf, (unsigned short*)nullptr, NTOK, 1536, DIMC, 3);
    // v: 1-segment, bf16 out
    gemm_bt<<<(NTOK / 128) * (768 / 128), 256, 0, stream>>>(
        x_hi, (unsigned short*)nullptr, w_hi + (size_t)1536 * DIMC, (unsigned short*)nullptr,
        (float*)nullptr, vbuf, NTOK, 768, DIMC, 1);

    attn_kernel<<<2048 * NHEAD, 256, 0, stream>>>(qkbuf, vbuf, attnout);

    // proj: 1-segment, fp32 out
    gemm_bt<<<(NTOK / 128) * (768 / 128), 256, 0, stream>>>(
        attnout, (unsigned short*)nullptr, p_hi, (unsigned short*)nullptr,
        out, (unsigned short*)nullptr, NTOK, 768, DIMC, 1);
}

// Round 2
// 2481.919 us; speedup vs baseline: 1.2528x; 1.2528x over previous
//
#include <hip/hip_runtime.h>
#include <cstdint>
#include <cstddef>

typedef __bf16 bf16x8 __attribute__((ext_vector_type(8)));
typedef float  f32x4  __attribute__((ext_vector_type(4)));

typedef __attribute__((address_space(1))) void v_as1;
typedef __attribute__((address_space(3))) void v_as3;

#define NTOK 100352      // 2*224*224
#define DIMC 768
#define NHEAD 12
#define IMG 224
#define WN 7
#define WL 49

__device__ __forceinline__ unsigned short f2bf(float f) {
    uint32_t u = __float_as_uint(f);
    uint32_t r = (u + 0x7FFFu + ((u >> 16) & 1u)) >> 16;
    return (unsigned short)r;
}
__device__ __forceinline__ float bf2f(unsigned short u) {
    return __uint_as_float(((uint32_t)u) << 16);
}

__device__ __forceinline__ void async_cp16(const void* g, void* l) {
    __builtin_amdgcn_global_load_lds((v_as1*)g, (v_as3*)l, 16, 0, 0);
}

// ---------------- hi/lo bf16 split ----------------
__global__ __launch_bounds__(256) void hilo_kernel(const float* __restrict__ in,
        unsigned short* __restrict__ hi, unsigned short* __restrict__ lo,
        int n4, int has_lo) {
    int idx = blockIdx.x * 256 + threadIdx.x;
    int stride = gridDim.x * 256;
    for (int i = idx; i < n4; i += stride) {
        float4 v = reinterpret_cast<const float4*>(in)[i];
        ushort4 h;
        h.x = f2bf(v.x); h.y = f2bf(v.y); h.z = f2bf(v.z); h.w = f2bf(v.w);
        reinterpret_cast<ushort4*>(hi)[i] = h;
        if (has_lo) {
            ushort4 l;
            l.x = f2bf(v.x - bf2f(h.x));
            l.y = f2bf(v.y - bf2f(h.y));
            l.z = f2bf(v.z - bf2f(h.z));
            l.w = f2bf(v.w - bf2f(h.w));
            reinterpret_cast<ushort4*>(lo)[i] = l;
        }
    }
}

// ---------------- 128x128x32 bf16 MFMA GEMM, C = A * B^T ----------------
// TRIPLE=1: C = Ahi*Bhi + Alo*Bhi + Ahi*Blo fused in one K-loop (48 MFMA/barrier).
// TRIPLE=0: C = Ahi*Bhi. Output fp32 (Cf) or bf16 (Cb).
#define BM 128
#define BN 128
#define BK 32
template <int TRIPLE>
__global__ __launch_bounds__(256) void gemm_bt(
    const unsigned short* __restrict__ Ahi, const unsigned short* __restrict__ Alo,
    const unsigned short* __restrict__ Bhi, const unsigned short* __restrict__ Blo,
    float* __restrict__ Cf, unsigned short* __restrict__ Cb,
    int M, int N, int K)
{
    __shared__ unsigned short lAh[BM * BK];
    __shared__ unsigned short lBh[BN * BK];
    __shared__ unsigned short lAl[BM * BK];
    __shared__ unsigned short lBl[BN * BK];

    const int tid  = threadIdx.x;
    const int wave = tid >> 6;
    const int lane = tid & 63;

    const int nTiles = N / BN;
    const int bm = blockIdx.x / nTiles;
    const int bn = blockIdx.x % nTiles;
    const int m0 = bm * BM, n0 = bn * BN;

    const int wm = (wave & 1) * 64;
    const int wn = (wave >> 1) * 64;

    f32x4 acc[4][4];
#pragma unroll
    for (int i = 0; i < 4; i++)
#pragma unroll
        for (int j = 0; j < 4; j++) acc[i][j] = (f32x4){0.f, 0.f, 0.f, 0.f};

    // staging: 512 chunks of 16B per tile; thread handles chunks tid and tid+256
    const int c0 = tid, c1 = tid + 256;
    const int ar0 = c0 >> 2, ac0 = (c0 & 3) * 8;
    const int ar1 = c1 >> 2, ac1 = (c1 & 3) * 8;
    const size_t off0 = (size_t)(wave * 64) * 8;        // + lane*16B by HW
    const size_t off1 = (size_t)(256 + wave * 64) * 8;

    const int lquad = lane >> 4;
    const int l16   = lane & 15;

    const unsigned short* AhB = Ahi + (size_t)m0 * K;
    const unsigned short* BhB = Bhi + (size_t)n0 * K;
    const unsigned short* AlB = TRIPLE ? Alo + (size_t)m0 * K : nullptr;
    const unsigned short* BlB = TRIPLE ? Blo + (size_t)n0 * K : nullptr;

    for (int kk = 0; kk < K; kk += BK) {
        async_cp16(AhB + (size_t)ar0 * K + kk + ac0, &lAh[off0]);
        async_cp16(AhB + (size_t)ar1 * K + kk + ac1, &lAh[off1]);
        async_cp16(BhB + (size_t)ar0 * K + kk + ac0, &lBh[off0]);
        async_cp16(BhB + (size_t)ar1 * K + kk + ac1, &lBh[off1]);
        if (TRIPLE) {
            async_cp16(AlB + (size_t)ar0 * K + kk + ac0, &lAl[off0]);
            async_cp16(AlB + (size_t)ar1 * K + kk + ac1, &lAl[off1]);
            async_cp16(BlB + (size_t)ar0 * K + kk + ac0, &lBl[off0]);
            async_cp16(BlB + (size_t)ar1 * K + kk + ac1, &lBl[off1]);
        }
        __syncthreads();
        bf16x8 ah[4], bh[4];
#pragma unroll
        for (int i = 0; i < 4; i++)
            ah[i] = *reinterpret_cast<const bf16x8*>(&lAh[(size_t)(wm + i * 16 + l16) * BK + lquad * 8]);
#pragma unroll
        for (int j = 0; j < 4; j++)
            bh[j] = *reinterpret_cast<const bf16x8*>(&lBh[(size_t)(wn + j * 16 + l16) * BK + lquad * 8]);
#pragma unroll
        for (int i = 0; i < 4; i++)
#pragma unroll
            for (int j = 0; j < 4; j++)
                acc[i][j] = __builtin_amdgcn_mfma_f32_16x16x32_bf16(ah[i], bh[j], acc[i][j], 0, 0, 0);
        if (TRIPLE) {
            bf16x8 al[4], bl[4];
#pragma unroll
            for (int i = 0; i < 4; i++)
                al[i] = *reinterpret_cast<const bf16x8*>(&lAl[(size_t)(wm + i * 16 + l16) * BK + lquad * 8]);
#pragma unroll
            for (int j = 0; j < 4; j++)
                bl[j] = *reinterpret_cast<const bf16x8*>(&lBl[(size_t)(wn + j * 16 + l16) * BK + lquad * 8]);
#pragma unroll
            for (int i = 0; i < 4; i++)
#pragma unroll
                for (int j = 0; j < 4; j++) {
                    acc[i][j] = __builtin_amdgcn_mfma_f32_16x16x32_bf16(al[i], bh[j], acc[i][j], 0, 0, 0);
                    acc[i][j] = __builtin_amdgcn_mfma_f32_16x16x32_bf16(ah[i], bl[j], acc[i][j], 0, 0, 0);
                }
        }
        __syncthreads();
    }

    // epilogue: C/D layout col = lane&15, row = (lane>>4)*4 + r
    if (Cf) {
#pragma unroll
        for (int i = 0; i < 4; i++) {
            int rb = m0 + wm + i * 16 + lquad * 4;
#pragma unroll
            for (int r = 0; r < 4; r++) {
                float* crow = Cf + (size_t)(rb + r) * N + n0 + wn + l16;
#pragma unroll
                for (int j = 0; j < 4; j++) crow[j * 16] = acc[i][j][r];
            }
        }
    } else {
#pragma unroll
        for (int i = 0; i < 4; i++) {
            int rb = m0 + wm + i * 16 + lquad * 4;
#pragma unroll
            for (int r = 0; r < 4; r++) {
                unsigned short* crow = Cb + (size_t)(rb + r) * N + n0 + wn + l16;
#pragma unroll
                for (int j = 0; j < 4; j++) crow[j * 16] = f2bf(acc[i][j][r]);
            }
        }
    }
}

// ---------------- windowed attention, one block per (window, head) ----------------
// Register-blocked 4x4 fp32 VALU with b128/b64 LDS reads.
// qk: NTOK x 1536 fp32 (q 0..767, k 768..1535); vbuf: NTOK x 768 bf16; attnout bf16.
__global__ __launch_bounds__(256) void attn_kernel(
    const float* __restrict__ qk,
    const unsigned short* __restrict__ vbuf,
    unsigned short* __restrict__ attnout)
{
    const int h   = blockIdx.x % NHEAD;
    const int win = blockIdx.x / NHEAD;
    const int b   = win >> 10;
    const int wy  = (win >> 5) & 31;
    const int wx  = win & 31;

    __shared__ __align__(16) float sq[52][68];          // q_hat * 10, RoPE'd
    __shared__ __align__(16) float sk[52][68];          // k_hat * 10
    __shared__ __align__(16) unsigned short sv[52][68]; // raw bf16 v
    __shared__ __align__(16) float sS[52][52];          // logits -> exp()
    __shared__ float rsum[WL];
    __shared__ int   rowidx[WL];

    const int tid = threadIdx.x;

    if (tid < WL) {
        int i = tid / WN, j = tid % WN;
        int ys = (wy * WN + i + 3) % IMG;
        int xs = (wx * WN + j + 3) % IMG;
        rowidx[tid] = b * (IMG * IMG) + ys * IMG + xs;
    }
    __syncthreads();

    // ---- stage q,k: one half-wave (32 lanes) per row; RoPE + fused 10/||.||
    const float LOG2_100_D16 = 0.41524101186092f;  // log2(100)/16
    {
        const int hw = tid >> 5;   // 0..7
        const int t  = tid & 31;   // pair (t, t+32)
        for (int pass = 0; pass < 7; ++pass) {
            int l = pass * 8 + hw;
            if (l < 49) {
                int i = l / WN, j = l % WN;
                float pos = (t < 16) ? (float)i : (float)j;
                float ang = pos * exp2f(-(float)(t & 15) * LOG2_100_D16);
                float s, c;
                __sincosf(ang, &s, &c);
                size_t base = (size_t)rowidx[l] * 1536 + h * 64;
                float q1 = qk[base + t], q2 = qk[base + t + 32];
                float k1 = qk[base + 768 + t], k2 = qk[base + 768 + t + 32];
                float nq = q1 * q1 + q2 * q2;
                float nk = k1 * k1 + k2 * k2;
#pragma unroll
                for (int m = 1; m < 32; m <<= 1) {
                    nq += __shfl_xor(nq, m);
                    nk += __shfl_xor(nk, m);
                }
                float iq = 10.f / fmaxf(sqrtf(nq), 1e-12f);  // fold sqrt(100) per side
                float ik = 10.f / fmaxf(sqrtf(nk), 1e-12f);
                sq[l][t]      = (q1 * c - q2 * s) * iq;
                sq[l][t + 32] = (q1 * s + q2 * c) * iq;
                sk[l][t]      = (k1 * c - k2 * s) * ik;
                sk[l][t + 32] = (k1 * s + k2 * c) * ik;
            } else if (l < 52) {
                sq[l][t] = 0.f; sq[l][t + 32] = 0.f;
                sk[l][t] = 0.f; sk[l][t + 32] = 0.f;
            }
        }
    }
    // ---- stage v (raw bf16), coalesced
    for (int e = tid; e < 52 * 64; e += 256) {
        int l = e >> 6, d = e & 63;
        sv[l][d] = (l < 49) ? vbuf[(size_t)rowidx[l] * 768 + h * 64 + d] : (unsigned short)0;
    }
    __syncthreads();

    // ---- scores: 13x13 tiles of 4x4, b128 LDS reads, 64 FMA per 8 reads
    if (tid < 169) {
        int ta = tid / 13, tb = tid - ta * 13;
        int a0 = ta * 4, b0 = tb * 4;
        float acc[4][4];
#pragma unroll
        for (int i = 0; i < 4; i++)
#pragma unroll
            for (int j = 0; j < 4; j++) acc[i][j] = 0.f;
#pragma unroll 4
        for (int d4 = 0; d4 < 16; ++d4) {
            float4 qa[4], kb[4];
#pragma unroll
            for (int i = 0; i < 4; i++) qa[i] = *reinterpret_cast<const float4*>(&sq[a0 + i][d4 * 4]);
#pragma unroll
            for (int j = 0; j < 4; j++) kb[j] = *reinterpret_cast<const float4*>(&sk[b0 + j][d4 * 4]);
#pragma unroll
            for (int i = 0; i < 4; i++)
#pragma unroll
                for (int j = 0; j < 4; j++)
                    acc[i][j] += qa[i].x * kb[j].x + qa[i].y * kb[j].y +
                                 qa[i].z * kb[j].z + qa[i].w * kb[j].w;
        }
#pragma unroll
        for (int i = 0; i < 4; i++) {
            float4 r;
            r.x = (b0 + 0 < WL) ? acc[i][0] : -1e30f;
            r.y = (b0 + 1 < WL) ? acc[i][1] : -1e30f;
            r.z = (b0 + 2 < WL) ? acc[i][2] : -1e30f;
            r.w = (b0 + 3 < WL) ? acc[i][3] : -1e30f;
            *reinterpret_cast<float4*>(&sS[a0 + i][b0]) = r;
        }
    }
    __syncthreads();

    // ---- softmax: 4 lanes per row
    if (tid < WL * 4) {
        int a = tid >> 2, s4 = tid & 3;
        float m = -1e30f;
        for (int bb = s4; bb < WL; bb += 4) m = fmaxf(m, sS[a][bb]);
        m = fmaxf(m, __shfl_xor(m, 1));
        m = fmaxf(m, __shfl_xor(m, 2));
        float sum = 0.f;
        for (int bb = s4; bb < WL; bb += 4) {
            float p = __expf(sS[a][bb] - m);
            sS[a][bb] = p;
            sum += p;
        }
        sum += __shfl_xor(sum, 1);
        sum += __shfl_xor(sum, 2);
        if (s4 == 0) rsum[a] = 1.f / sum;
    }
    __syncthreads();

    // ---- O = P V : 13x16 tiles of 4x4, bf16 V via b64 reads
    if (tid < 208) {
        int ta = tid >> 4, td = tid & 15;
        int a0 = ta * 4, d0 = td * 4;
        float acc[4][4];
#pragma unroll
        for (int i = 0; i < 4; i++)
#pragma unroll
            for (int j = 0; j < 4; j++) acc[i][j] = 0.f;
        for (int bb = 0; bb < WL; ++bb) {
            float p0 = sS[a0 + 0][bb], p1 = sS[a0 + 1][bb];
            float p2 = sS[a0 + 2][bb], p3 = sS[a0 + 3][bb];
            ushort4 vr = *reinterpret_cast<const ushort4*>(&sv[bb][d0]);
            float v0 = bf2f(vr.x), v1 = bf2f(vr.y), v2 = bf2f(vr.z), v3 = bf2f(vr.w);
            acc[0][0] += p0 * v0; acc[0][1] += p0 * v1; acc[0][2] += p0 * v2; acc[0][3] += p0 * v3;
            acc[1][0] += p1 * v0; acc[1][1] += p1 * v1; acc[1][2] += p1 * v2; acc[1][3] += p1 * v3;
            acc[2][0] += p2 * v0; acc[2][1] += p2 * v1; acc[2][2] += p2 * v2; acc[2][3] += p2 * v3;
            acc[3][0] += p3 * v0; acc[3][1] += p3 * v1; acc[3][2] += p3 * v2; acc[3][3] += p3 * v3;
        }
#pragma unroll
        for (int i = 0; i < 4; i++) {
            int a = a0 + i;
            if (a < WL) {
                float r = rsum[a];
                ushort4 o;
                o.x = f2bf(acc[i][0] * r);
                o.y = f2bf(acc[i][1] * r);
                o.z = f2bf(acc[i][2] * r);
                o.w = f2bf(acc[i][3] * r);
                *reinterpret_cast<ushort4*>(&attnout[(size_t)rowidx[a] * 768 + h * 64 + d0]) = o;
            }
        }
    }
}

extern "C" void kernel_launch(void* const* d_in, const int* in_sizes, int n_in,
                              void* d_out, int out_size, void* d_ws, size_t ws_size,
                              hipStream_t stream) {
    const float* x      = (const float*)d_in[0];
    const float* qkv_w  = (const float*)d_in[1];
    const float* proj_w = (const float*)d_in[2];
    float* out = (float*)d_out;

    char* ws = (char*)d_ws;
    const size_t XE    = (size_t)NTOK * DIMC;
    const size_t WQKV  = (size_t)3 * DIMC * DIMC;
    const size_t WPROJ = (size_t)DIMC * DIMC;

    unsigned short* x_hi = (unsigned short*)ws;
    unsigned short* x_lo = x_hi + XE;
    unsigned short* w_hi = x_lo + XE;
    unsigned short* w_lo = w_hi + WQKV;
    unsigned short* p_hi = w_lo + WQKV;
    float* qkbuf = (float*)(p_hi + WPROJ);
    unsigned short* vbuf    = x_lo;   // overlay: x_lo dead after qk GEMM
    unsigned short* attnout = x_hi;   // overlay: x_hi dead after v GEMM

    size_t need = (size_t)((char*)(qkbuf + (size_t)NTOK * 1536) - ws);
    if (ws_size < need) return;

    hilo_kernel<<<8192, 256, 0, stream>>>(x, x_hi, x_lo, (int)(XE / 4), 1);
    hilo_kernel<<<1728, 256, 0, stream>>>(qkv_w, w_hi, w_lo, (int)(WQKV / 4), 1);
    hilo_kernel<<<576, 256, 0, stream>>>(proj_w, p_hi, (unsigned short*)nullptr, (int)(WPROJ / 4), 0);

    // q,k: fused 3-term split-bf16, fp32 out
    gemm_bt<1><<<(NTOK / 128) * (1536 / 128), 256, 0, stream>>>(
        x_hi, x_lo, w_hi, w_lo, qkbuf, (unsigned short*)nullptr, NTOK, 1536, DIMC);
    // v: single, bf16 out
    gemm_bt<0><<<(NTOK / 128) * (768 / 128), 256, 0, stream>>>(
        x_hi, (unsigned short*)nullptr, w_hi + (size_t)1536 * DIMC, (unsigned short*)nullptr,
        (float*)nullptr, vbuf, NTOK, 768, DIMC);

    attn_kernel<<<2048 * NHEAD, 256, 0, stream>>>(qkbuf, vbuf, attnout);

    // proj: single, fp32 out
    gemm_bt<0><<<(NTOK / 128) * (768 / 128), 256, 0, stream>>>(
        attnout, (unsigned short*)nullptr, p_hi, (unsigned short*)nullptr,
        out, (unsigned short*)nullptr, NTOK, 768, DIMC);
}